// Round 4
// baseline (271.913 us; speedup 1.0000x reference)
//
#include <hip/hip_runtime.h>

typedef unsigned short u16;
typedef unsigned int u32;
typedef __attribute__((ext_vector_type(4))) float f32x4;
typedef __attribute__((ext_vector_type(8))) __bf16 bf16x8;
typedef __attribute__((ext_vector_type(4))) _Float16 f16x4;
typedef __attribute__((ext_vector_type(4))) u16 u16x4;
typedef __attribute__((ext_vector_type(4))) u32 u32x4;

#define D_ 1024
#define S_ 2048
#define B_ 4
#define H_ 16
#define HD_ 64
#define M_ 8192
#define LDP 72
#define QSCALE 0.18033688011112042591f /* 0.125 * log2(e) */

__device__ __forceinline__ u16 f2bf(float f) {
  u32 u = __float_as_uint(f);
  u += 0x7fffu + ((u >> 16) & 1u);
  return (u16)(u >> 16);
}

// ---------------- cast x (fp32 -> bf16) ----------------
__global__ __launch_bounds__(256) void cast_x_kernel(const float* __restrict__ x,
                                                     u16* __restrict__ xb) {
  int i = (blockIdx.x * 256 + threadIdx.x) * 4;
  f32x4 v = *(const f32x4*)(x + i);
  u16x4 o = {f2bf(v[0]), f2bf(v[1]), f2bf(v[2]), f2bf(v[3])};
  *(u16x4*)(xb + i) = o;
}

// ---------------- transpose+cast weights: Wt[n][k] = bf16(W[k][n]) ----------------
__global__ __launch_bounds__(256) void wtrans_kernel(const float* __restrict__ Wq, const float* __restrict__ Wk,
                                                     const float* __restrict__ Wv, const float* __restrict__ Wo,
                                                     u16* __restrict__ Wqt, u16* __restrict__ Wkt,
                                                     u16* __restrict__ Wvt, u16* __restrict__ Wot) {
  __shared__ float lds[64][65];
  const float* W = blockIdx.z == 0 ? Wq : blockIdx.z == 1 ? Wk : blockIdx.z == 2 ? Wv : Wo;
  u16* Wt       = blockIdx.z == 0 ? Wqt : blockIdx.z == 1 ? Wkt : blockIdx.z == 2 ? Wvt : Wot;
  int k0 = blockIdx.x * 64, n0 = blockIdx.y * 64;
  int tr = threadIdx.x >> 6, tc = threadIdx.x & 63;
#pragma unroll
  for (int i = 0; i < 16; ++i)
    lds[tr + i * 4][tc] = W[(size_t)(k0 + tr + i * 4) * D_ + n0 + tc];
  __syncthreads();
#pragma unroll
  for (int i = 0; i < 16; ++i)
    Wt[(size_t)(n0 + tr + i * 4) * D_ + k0 + tc] = f2bf(lds[tc][tr + i * 4]);
}

// ---------------- shared 128x128 GEMM mainloop (A row-major, Bt = B^T row-major) ----------------
__device__ __forceinline__ void gemm_main(const u16* __restrict__ A, const u16* __restrict__ Bt,
                                          u16* As, u16* Bs, int row0, int col0, f32x4 acc[4][4]) {
  const int tid = threadIdx.x;
  const int lane = tid & 63, wave = tid >> 6;
  const int wr = wave >> 1, wc = wave & 1;
  const int l15 = lane & 15, lg = lane >> 4;
#pragma unroll 1
  for (int k0 = 0; k0 < D_; k0 += 64) {
    __syncthreads();
#pragma unroll
    for (int it = 0; it < 4; ++it) {
      int idx = it * 256 + tid;
      int r = idx >> 3, c = (idx & 7) << 3;
      *(u32x4*)(As + r * LDP + c) = *(const u32x4*)(A + (size_t)(row0 + r) * D_ + k0 + c);
      *(u32x4*)(Bs + r * LDP + c) = *(const u32x4*)(Bt + (size_t)(col0 + r) * D_ + k0 + c);
    }
    __syncthreads();
#pragma unroll
    for (int kk = 0; kk < 64; kk += 32) {
      bf16x8 af[4], bf[4];
#pragma unroll
      for (int m = 0; m < 4; ++m)
        af[m] = *(const bf16x8*)(As + (wr * 64 + m * 16 + l15) * LDP + kk + lg * 8);
#pragma unroll
      for (int n = 0; n < 4; ++n)
        bf[n] = *(const bf16x8*)(Bs + (wc * 64 + n * 16 + l15) * LDP + kk + lg * 8);
#pragma unroll
      for (int m = 0; m < 4; ++m)
#pragma unroll
        for (int n = 0; n < 4; ++n)
          acc[m][n] = __builtin_amdgcn_mfma_f32_16x16x32_bf16(af[m], bf[n], acc[m][n], 0, 0, 0);
    }
  }
}

// ---------------- QKV projection GEMM (1D grid, XCD-clustered swizzle) ----------------
// lin%8 = XCD cluster; per XCD: z outer, then 8 row-panels x 8 col-tiles (A panel + one W fit L2).
__global__ __launch_bounds__(256) void qkv_gemm_kernel(const u16* __restrict__ xb,
                                                       const u16* __restrict__ Wqt, const u16* __restrict__ Wkt,
                                                       const u16* __restrict__ Wvt,
                                                       u16* __restrict__ Qb, u16* __restrict__ Kb,
                                                       _Float16* __restrict__ Vt) {
  __shared__ u16 As[128 * LDP];
  __shared__ u16 Bs[128 * LDP];
  int lin = blockIdx.x;
  int xcd = lin & 7, pos = lin >> 3;      // pos in [0,192)
  int mode = pos / 64;                    // z outer
  int rem = pos & 63;
  int by = xcd * 8 + (rem >> 3);          // row-panel
  int bx = rem & 7;                       // col-tile
  const u16* Bt = mode == 0 ? Wqt : mode == 1 ? Wkt : Wvt;
  f32x4 acc[4][4] = {};
  int row0 = by * 128, col0 = bx * 128;
  gemm_main(xb, Bt, As, Bs, row0, col0, acc);
  int lane = threadIdx.x & 63, wave = threadIdx.x >> 6;
  int wr = wave >> 1, wc = wave & 1, l15 = lane & 15, lg = lane >> 4;
  int rbase = row0 + wr * 64 + lg * 4, cbase = col0 + wc * 64 + l15;
  if (mode == 2) {
#pragma unroll
    for (int m = 0; m < 4; ++m) {
      int row = rbase + m * 16;
      int b = row >> 11, s = row & (S_ - 1);
#pragma unroll
      for (int n = 0; n < 4; ++n) {
        int col = cbase + n * 16;
        int h = col >> 6, hd = col & 63;
        f16x4 vv = {(_Float16)acc[m][n][0], (_Float16)acc[m][n][1],
                    (_Float16)acc[m][n][2], (_Float16)acc[m][n][3]};
        *(f16x4*)(Vt + ((size_t)((b << 4) + h) * HD_ + hd) * S_ + s) = vv;
      }
    }
  } else {
    u16* dst = mode == 0 ? Qb : Kb;
    float scl = mode == 0 ? QSCALE : 1.0f;
#pragma unroll
    for (int m = 0; m < 4; ++m)
#pragma unroll
      for (int n = 0; n < 4; ++n) {
        int col = cbase + n * 16;
#pragma unroll
        for (int r = 0; r < 4; ++r) {
          int row = rbase + m * 16 + r;
          dst[(size_t)row * D_ + col] = f2bf(acc[m][n][r] * scl);
        }
      }
  }
}

// ---------------- fused causal flash attention, v3 ----------------
// Block = 4 waves, 128 q rows, one (b,h). Wave w owns rows [w*32, w*32+32): two 16-row frags.
// KV tile = 64 staged in LDS (shared), double-buffered, async-stage order.
// Swapped QK^T: s = mfma(K,Q) => lane owns q = lane&15, kv = j*16 + (lane>>4)*4 + r.
// That layout IS the B-fragment of mfma_f32_16x16x16f16, so PV needs no cross-lane movement.
// K LDS reads are shared by both q-frags (8 b128 -> 16 MFMA); V reads by both (16 b64 -> 32 MFMA).
__global__ __launch_bounds__(256) void attn_kernel(const u16* __restrict__ Qb, const u16* __restrict__ Kb,
                                                   const _Float16* __restrict__ Vt, u16* __restrict__ attnb) {
  __shared__ u16 Ks[2][64][LDP];       // [kv][hd]
  __shared__ _Float16 Vs[2][HD_][LDP]; // [hd][kv]
  const int tid = threadIdx.x;
  const int wave = tid >> 6, lane = tid & 63;
  const int l15 = lane & 15, lg = lane >> 4;
  const int bh = blockIdx.y, b = bh >> 4, h = bh & 15;
  const int qblk = gridDim.x - 1 - blockIdx.x;  // LPT: biggest first
  const int q0b = qblk * 128;
  const int ntiles = 2 * qblk + 2;
  const int wq0 = q0b + wave * 32;  // frag0 rows [wq0,wq0+16), frag1 [wq0+16,wq0+32)

  const u16* Qrow = Qb + (size_t)(b * S_ + wq0 + l15) * D_ + h * HD_;
  bf16x8 qf00 = *(const bf16x8*)(Qrow + lg * 8);
  bf16x8 qf01 = *(const bf16x8*)(Qrow + 32 + lg * 8);
  bf16x8 qf10 = *(const bf16x8*)(Qrow + (size_t)16 * D_ + lg * 8);
  bf16x8 qf11 = *(const bf16x8*)(Qrow + (size_t)16 * D_ + 32 + lg * 8);

  // staging geometry: thread t covers rows {t>>3, 32+(t>>3)}, 16B chunk (t&7)*16 bytes
  const int srow = tid >> 3;
  const int scol = (tid & 7) * 8;  // in u16/f16 elems (16B)
  const u16* Kg = Kb + (size_t)(b * S_) * D_ + h * HD_;
  const _Float16* Vg = Vt + (size_t)bh * HD_ * S_;

  float m0 = -1e30f, m1 = -1e30f, l0 = 0.f, l1 = 0.f;
  f32x4 o0[4] = {}, o1[4] = {};
  u32x4 kreg0, kreg1, vreg0, vreg1;

  // prologue: tile 0 -> regs -> LDS buf0
  kreg0 = *(const u32x4*)(Kg + (size_t)(srow) * D_ + scol);
  kreg1 = *(const u32x4*)(Kg + (size_t)(32 + srow) * D_ + scol);
  vreg0 = *(const u32x4*)(Vg + (size_t)srow * S_ + scol);
  vreg1 = *(const u32x4*)(Vg + (size_t)(32 + srow) * S_ + scol);
  *(u32x4*)(&Ks[0][srow][scol]) = kreg0;
  *(u32x4*)(&Ks[0][32 + srow][scol]) = kreg1;
  *(u32x4*)(&Vs[0][srow][scol]) = vreg0;
  *(u32x4*)(&Vs[0][32 + srow][scol]) = vreg1;

#pragma unroll 1
  for (int t = 0; t < ntiles; ++t) {
    const int cur = t & 1;
    const int kv0 = t * 64;
    __syncthreads();  // tile t visible in buf[cur]
    // issue global loads for tile t+1 (overlap with compute below)
    if (t + 1 < ntiles) {
      int nkv = kv0 + 64;
      kreg0 = *(const u32x4*)(Kg + (size_t)(nkv + srow) * D_ + scol);
      kreg1 = *(const u32x4*)(Kg + (size_t)(nkv + 32 + srow) * D_ + scol);
      vreg0 = *(const u32x4*)(Vg + (size_t)srow * S_ + nkv + scol);
      vreg1 = *(const u32x4*)(Vg + (size_t)(32 + srow) * S_ + nkv + scol);
    }
    const bool act0 = kv0 <= wq0 + 15;
    const bool act1 = kv0 <= wq0 + 31;

    // softmax helper (per fragment)
    auto softmax_frag = [&](f32x4 s[4], float& mm, float& ll, f32x4 oo[4], f16x4 pb[4],
                            int qr, bool domask) {
      if (domask) {
#pragma unroll
        for (int j = 0; j < 4; ++j)
#pragma unroll
          for (int r = 0; r < 4; ++r)
            if (kv0 + j * 16 + lg * 4 + r > qr) s[j][r] = -1e30f;
      }
      float t0 = fmaxf(fmaxf(s[0][0], s[0][1]), fmaxf(s[0][2], s[0][3]));
      float t1 = fmaxf(fmaxf(s[1][0], s[1][1]), fmaxf(s[1][2], s[1][3]));
      float t2 = fmaxf(fmaxf(s[2][0], s[2][1]), fmaxf(s[2][2], s[2][3]));
      float t3 = fmaxf(fmaxf(s[3][0], s[3][1]), fmaxf(s[3][2], s[3][3]));
      float tmax = fmaxf(fmaxf(t0, t1), fmaxf(t2, t3));
      tmax = fmaxf(tmax, __shfl_xor(tmax, 16));
      tmax = fmaxf(tmax, __shfl_xor(tmax, 32));
      if (!__all(tmax - mm <= 8.f)) {  // defer-max (T13)
        float nm = fmaxf(mm, tmax);
        float alpha = exp2f(mm - nm);
        mm = nm;
        ll *= alpha;
#pragma unroll
        for (int hf = 0; hf < 4; ++hf) oo[hf] *= alpha;
      }
#pragma unroll
      for (int j = 0; j < 4; ++j) {
        float p0 = exp2f(s[j][0] - mm), p1 = exp2f(s[j][1] - mm);
        float p2 = exp2f(s[j][2] - mm), p3 = exp2f(s[j][3] - mm);
        ll += (p0 + p1) + (p2 + p3);
        pb[j] = (f16x4){(_Float16)p0, (_Float16)p1, (_Float16)p2, (_Float16)p3};
      }
    };

    if (act1) {
      f32x4 s0[4], s1[4];
      __builtin_amdgcn_s_setprio(1);
      if (act0) {
#pragma unroll
        for (int j = 0; j < 4; ++j) {
          bf16x8 kf0 = *(const bf16x8*)(&Ks[cur][j * 16 + l15][lg * 8]);
          bf16x8 kf1 = *(const bf16x8*)(&Ks[cur][j * 16 + l15][32 + lg * 8]);
          f32x4 z0 = {0.f, 0.f, 0.f, 0.f}, z1 = {0.f, 0.f, 0.f, 0.f};
          z0 = __builtin_amdgcn_mfma_f32_16x16x32_bf16(kf0, qf00, z0, 0, 0, 0);
          z1 = __builtin_amdgcn_mfma_f32_16x16x32_bf16(kf0, qf10, z1, 0, 0, 0);
          z0 = __builtin_amdgcn_mfma_f32_16x16x32_bf16(kf1, qf01, z0, 0, 0, 0);
          z1 = __builtin_amdgcn_mfma_f32_16x16x32_bf16(kf1, qf11, z1, 0, 0, 0);
          s0[j] = z0;
          s1[j] = z1;
        }
      } else {
#pragma unroll
        for (int j = 0; j < 4; ++j) {
          bf16x8 kf0 = *(const bf16x8*)(&Ks[cur][j * 16 + l15][lg * 8]);
          bf16x8 kf1 = *(const bf16x8*)(&Ks[cur][j * 16 + l15][32 + lg * 8]);
          f32x4 z1 = {0.f, 0.f, 0.f, 0.f};
          z1 = __builtin_amdgcn_mfma_f32_16x16x32_bf16(kf0, qf10, z1, 0, 0, 0);
          z1 = __builtin_amdgcn_mfma_f32_16x16x32_bf16(kf1, qf11, z1, 0, 0, 0);
          s1[j] = z1;
        }
      }
      __builtin_amdgcn_s_setprio(0);

      f16x4 pb0[4], pb1[4];
      const bool dm0 = kv0 + 63 > wq0;
      const bool dm1 = kv0 + 63 > wq0 + 16;
      if (act0) softmax_frag(s0, m0, l0, o0, pb0, wq0 + l15, dm0);
      softmax_frag(s1, m1, l1, o1, pb1, wq0 + 16 + l15, dm1);

      __builtin_amdgcn_s_setprio(1);
      if (act0) {
#pragma unroll
        for (int j = 0; j < 4; ++j)
#pragma unroll
          for (int hf = 0; hf < 4; ++hf) {
            f16x4 vf = *(const f16x4*)(&Vs[cur][hf * 16 + l15][j * 16 + lg * 4]);
            o0[hf] = __builtin_amdgcn_mfma_f32_16x16x16f16(vf, pb0[j], o0[hf], 0, 0, 0);
            o1[hf] = __builtin_amdgcn_mfma_f32_16x16x16f16(vf, pb1[j], o1[hf], 0, 0, 0);
          }
      } else {
#pragma unroll
        for (int j = 0; j < 4; ++j)
#pragma unroll
          for (int hf = 0; hf < 4; ++hf) {
            f16x4 vf = *(const f16x4*)(&Vs[cur][hf * 16 + l15][j * 16 + lg * 4]);
            o1[hf] = __builtin_amdgcn_mfma_f32_16x16x16f16(vf, pb1[j], o1[hf], 0, 0, 0);
          }
      }
      __builtin_amdgcn_s_setprio(0);
    }

    // ---- write tile t+1 into the other buffer (all waves passed top barrier) ----
    if (t + 1 < ntiles) {
      const int nxt = cur ^ 1;
      *(u32x4*)(&Ks[nxt][srow][scol]) = kreg0;
      *(u32x4*)(&Ks[nxt][32 + srow][scol]) = kreg1;
      *(u32x4*)(&Vs[nxt][srow][scol]) = vreg0;
      *(u32x4*)(&Vs[nxt][32 + srow][scol]) = vreg1;
    }
  }

  // ---- epilogue: reduce lsum across lane-groups, normalize, store both frags ----
  l0 += __shfl_xor(l0, 16);
  l0 += __shfl_xor(l0, 32);
  l1 += __shfl_xor(l1, 16);
  l1 += __shfl_xor(l1, 32);
  float inv0 = 1.0f / l0, inv1 = 1.0f / l1;
  u16* Orow = attnb + (size_t)(b * S_ + wq0 + l15) * D_ + h * HD_ + lg * 4;
#pragma unroll
  for (int hf = 0; hf < 4; ++hf) {
    u16x4 ov = {f2bf(o0[hf][0] * inv0), f2bf(o0[hf][1] * inv0),
                f2bf(o0[hf][2] * inv0), f2bf(o0[hf][3] * inv0)};
    *(u16x4*)(Orow + hf * 16) = ov;
  }
  u16* Orow1 = Orow + (size_t)16 * D_;
#pragma unroll
  for (int hf = 0; hf < 4; ++hf) {
    u16x4 ov = {f2bf(o1[hf][0] * inv1), f2bf(o1[hf][1] * inv1),
                f2bf(o1[hf][2] * inv1), f2bf(o1[hf][3] * inv1)};
    *(u16x4*)(Orow1 + hf * 16) = ov;
  }
}

// ---------------- output projection GEMM (fp32 out + bias, XCD-clustered swizzle) ----------------
__global__ __launch_bounds__(256) void out_gemm_kernel(const u16* __restrict__ attnb, const u16* __restrict__ Wot,
                                                       const float* __restrict__ bo, float* __restrict__ outp) {
  __shared__ u16 As[128 * LDP];
  __shared__ u16 Bs[128 * LDP];
  int lin = blockIdx.x;
  int xcd = lin & 7, pos = lin >> 3;  // pos in [0,64)
  int by = xcd * 8 + (pos >> 3);
  int bx = pos & 7;
  f32x4 acc[4][4] = {};
  int row0 = by * 128, col0 = bx * 128;
  gemm_main(attnb, Wot, As, Bs, row0, col0, acc);
  int lane = threadIdx.x & 63, wave = threadIdx.x >> 6;
  int wr = wave >> 1, wc = wave & 1, l15 = lane & 15, lg = lane >> 4;
  int rbase = row0 + wr * 64 + lg * 4, cbase = col0 + wc * 64 + l15;
#pragma unroll
  for (int n = 0; n < 4; ++n) {
    float bn = bo[cbase + n * 16];
#pragma unroll
    for (int m = 0; m < 4; ++m)
#pragma unroll
      for (int r = 0; r < 4; ++r)
        outp[(size_t)(rbase + m * 16 + r) * D_ + cbase + n * 16] = acc[m][n][r] + bn;
  }
}

extern "C" void kernel_launch(void* const* d_in, const int* in_sizes, int n_in,
                              void* d_out, int out_size, void* d_ws, size_t ws_size,
                              hipStream_t stream) {
  const float* x  = (const float*)d_in[0];
  const float* Wq = (const float*)d_in[1];
  const float* Wk = (const float*)d_in[2];
  const float* Wv = (const float*)d_in[3];
  const float* Wo = (const float*)d_in[4];
  const float* bo = (const float*)d_in[5];
  float* outp = (float*)d_out;

  char* ws = (char*)d_ws;
  u16* xb        = (u16*)(ws);                          // 16 MiB
  u16* Wqt       = (u16*)(ws + ((size_t)16 << 20));     // 2 MiB
  u16* Wkt       = (u16*)(ws + ((size_t)18 << 20));
  u16* Wvt       = (u16*)(ws + ((size_t)20 << 20));
  u16* Wot       = (u16*)(ws + ((size_t)22 << 20));
  u16* Qb        = (u16*)(ws + ((size_t)24 << 20));     // 16 MiB
  u16* Kb        = (u16*)(ws + ((size_t)40 << 20));     // 16 MiB
  _Float16* Vt   = (_Float16*)(ws + ((size_t)56 << 20));// 16 MiB
  u16* attnb     = (u16*)(ws + ((size_t)72 << 20));     // 16 MiB

  cast_x_kernel<<<dim3(M_ * D_ / (256 * 4)), dim3(256), 0, stream>>>(x, xb);
  wtrans_kernel<<<dim3(16, 16, 4), dim3(256), 0, stream>>>(Wq, Wk, Wv, Wo, Wqt, Wkt, Wvt, Wot);
  qkv_gemm_kernel<<<dim3(1536), dim3(256), 0, stream>>>(xb, Wqt, Wkt, Wvt, Qb, Kb, Vt);
  attn_kernel<<<dim3(S_ / 128, B_ * H_), dim3(256), 0, stream>>>(Qb, Kb, Vt, attnb);
  out_gemm_kernel<<<dim3(512), dim3(256), 0, stream>>>(attnb, Wot, bo, outp);
}